// Round 4
// baseline (443.115 us; speedup 1.0000x reference)
//
#include <hip/hip_runtime.h>
#include <hip/hip_bf16.h>

#define N 8192
#define FIN 128
#define FOUT 64
#define ALPHA 0.2f
#define LOG2E 1.44269504f
#define JPW (N / 8)       // j-range per wave in k_attn (8 waves/block)
#define UNITS (JPW / 32)  // 32 K-steps of 32 j each

typedef __attribute__((ext_vector_type(8))) short short8;
typedef __attribute__((ext_vector_type(4))) float f32x4;

static __device__ __forceinline__ unsigned fkey(float x) {
    unsigned u = __float_as_uint(x);
    return (u >> 31) ? ~u : (u | 0x80000000u);
}
static __device__ __forceinline__ float fdecode(unsigned k) {
    unsigned u = (k & 0x80000000u) ? (k & 0x7FFFFFFFu) : ~k;
    return __uint_as_float(u);
}

// ---------------- k_prep: Wh = h@W (fp32), s = Wh@a1, t = Wh@a2, global max keys ----
__global__ __launch_bounds__(256) void k_prep(const float* __restrict__ h,
                                              const float* __restrict__ W,
                                              const float* __restrict__ a,
                                              float* __restrict__ Wh,
                                              float* __restrict__ s,
                                              float* __restrict__ t,
                                              unsigned* __restrict__ keys) {
    __shared__ float lH[16 * FIN];    // 8 KB
    __shared__ float lW[FIN * FOUT];  // 32 KB
    __shared__ float red[8];
    const int tid = threadIdx.x;
    const int r0 = blockIdx.x * 16;
    {   // coalesced float4 staging
        const float4* src = (const float4*)(h + (size_t)r0 * FIN);
        float4* dst = (float4*)lH;
        for (int i = tid; i < 16 * FIN / 4; i += 256) dst[i] = src[i];
        const float4* ws_ = (const float4*)W;
        float4* dw = (float4*)lW;
        for (int i = tid; i < FIN * FOUT / 4; i += 256) dw[i] = ws_[i];
    }
    __syncthreads();
    const int wave = tid >> 6, lane = tid & 63;
    float acc[4] = {0.f, 0.f, 0.f, 0.f};
    for (int k = 0; k < FIN; ++k) {
        float wv = lW[k * FOUT + lane];
#pragma unroll
        for (int r = 0; r < 4; ++r)
            acc[r] = fmaf(lH[(wave * 4 + r) * FIN + k], wv, acc[r]);
    }
    const float a1 = a[lane], a2 = a[FOUT + lane];
    float smx = -1e30f, tmx = -1e30f;
#pragma unroll
    for (int r = 0; r < 4; ++r) {
        int row = r0 + wave * 4 + r;
        Wh[(size_t)row * FOUT + lane] = acc[r];
        float sv = acc[r] * a1, tv = acc[r] * a2;
#pragma unroll
        for (int off = 32; off; off >>= 1) {
            sv += __shfl_xor(sv, off);
            tv += __shfl_xor(tv, off);
        }
        if (lane == 0) { s[row] = sv; t[row] = tv; }
        smx = fmaxf(smx, sv);  // shfl_xor chain leaves full sum on every lane
        tmx = fmaxf(tmx, tv);
    }
    if (lane == 0) { red[wave] = smx; red[4 + wave] = tmx; }
    __syncthreads();
    if (tid == 0) {
        float ms = fmaxf(fmaxf(red[0], red[1]), fmaxf(red[2], red[3]));
        float mt = fmaxf(fmaxf(red[4], red[5]), fmaxf(red[6], red[7]));
        atomicMax(keys + 0, fkey(ms));   // one atomic per block: low contention
        atomicMax(keys + 1, fkey(mt));
    }
}

// ---------------- k_pack: Wh fp32 -> bf16 B-fragment layout ------------------------
// B-frag (16x16x32): lane holds col n = lane&15, k = (lane>>4)*8 + e, e=0..7
__global__ __launch_bounds__(256) void k_pack(const float* __restrict__ Wh,
                                              __hip_bfloat16* __restrict__ WhB) {
    const int c = blockIdx.x;            // k-chunk 0..255
    const int tn = threadIdx.x >> 6;     // col tile 0..3
    const int lane = threadIdx.x & 63;
    const int quad = lane >> 4, l16 = lane & 15;
    const float* src = Wh + ((size_t)(c * 32 + quad * 8)) * FOUT + tn * 16 + l16;
    union { unsigned short u[8]; short8 v; } frag;
#pragma unroll
    for (int e = 0; e < 8; ++e) {
        __hip_bfloat16 b = __float2bfloat16(src[(size_t)e * FOUT]);
        frag.u[e] = *(unsigned short*)&b;
    }
    *(short8*)&WhB[(((size_t)c * 4 + tn) * 64 + lane) * 8] = frag.v;
}

// ---------------- k_attn: fused mask+softmax+PV via MFMA ---------------------------
// adj (HBM, 900cy) pipelined depth-4; t/B (L2, ~200cy) pipelined depth-2.
static __device__ __forceinline__ void proc_unit(const float4& a0, const float4& a1,
                                                 const float4& t0, const float4& t1,
                                                 const short8& b0, const short8& b1,
                                                 const short8& b2, const short8& b3,
                                                 float sm, float mm,
                                                 f32x4& acc0, f32x4& acc1,
                                                 f32x4& acc2, f32x4& acc3,
                                                 float& lsum) {
    union { unsigned short u16[8]; short8 v; } af;
    const float* ap0 = (const float*)&a0;
    const float* ap1 = (const float*)&a1;
    const float* tp0 = (const float*)&t0;
    const float* tp1 = (const float*)&t1;
#pragma unroll
    for (int e = 0; e < 8; ++e) {
        float av = (e < 4) ? ap0[e] : ap1[e - 4];
        float tv = (e < 4) ? tp0[e] : tp1[e - 4];
        float x = sm + tv;
        float le = fmaxf(x, ALPHA * x);
        float ex = exp2f(fmaf(le, LOG2E, -mm));
        float p = av * ex;
        __hip_bfloat16 pb = __float2bfloat16(p);
        unsigned short ub = *(unsigned short*)&pb;
        af.u16[e] = ub;
        lsum += __uint_as_float(((unsigned)ub) << 16);  // consistent num/denom
    }
    acc0 = __builtin_amdgcn_mfma_f32_16x16x32_bf16(af.v, b0, acc0, 0, 0, 0);
    acc1 = __builtin_amdgcn_mfma_f32_16x16x32_bf16(af.v, b1, acc1, 0, 0, 0);
    acc2 = __builtin_amdgcn_mfma_f32_16x16x32_bf16(af.v, b2, acc2, 0, 0, 0);
    acc3 = __builtin_amdgcn_mfma_f32_16x16x32_bf16(af.v, b3, acc3, 0, 0, 0);
}

// Block: 512 thr = 8 waves; block owns 16 rows; wave w covers j in [w*1024,(w+1)*1024)
__global__ __launch_bounds__(512, 4) void k_attn(const float* __restrict__ adj,
                                                 const __hip_bfloat16* __restrict__ WhB,
                                                 const float* __restrict__ s,
                                                 const float* __restrict__ t,
                                                 const unsigned* __restrict__ keys,
                                                 float* __restrict__ out) {
    __shared__ float shacc[8][4][64][4];  // 32 KB [wave][tile][lane][reg]
    __shared__ float shl[8][16];
    const int wave = threadIdx.x >> 6, lane = threadIdx.x & 63;
    const int quad = lane >> 4, l16 = lane & 15;
    const int i0 = blockIdx.x * 16;

    const float* arow = adj + (size_t)(i0 + l16) * N + wave * JPW + quad * 8;
    const float* trow = t + wave * JPW + quad * 8;
    const short8* BF = (const short8*)WhB;

    // ---- prologue: fill adj pipe (depth 4) FIRST — these are the HBM misses ----
    float4 A0[4], A1[4];
#pragma unroll
    for (int d = 0; d < 4; ++d) {
        A0[d] = *(const float4*)(arow + d * 32);
        A1[d] = *(const float4*)(arow + d * 32 + 4);
    }
    // t/B pipe (depth 2, L2-resident)
    float4 T0[2], T1[2];
    short8 B0[2], B1[2], B2[2], B3[2];
#pragma unroll
    for (int d = 0; d < 2; ++d) {
        T0[d] = *(const float4*)(trow + d * 32);
        T1[d] = *(const float4*)(trow + d * 32 + 4);
        const size_t cidx = ((size_t)(wave * UNITS + d)) * 4;
        B0[d] = BF[(cidx + 0) * 64 + lane];
        B1[d] = BF[(cidx + 1) * 64 + lane];
        B2[d] = BF[(cidx + 2) * 64 + lane];
        B3[d] = BF[(cidx + 3) * 64 + lane];
    }

    const float mraw = fdecode(keys[0]) + fdecode(keys[1]);
    const float mle = mraw > 0.f ? mraw : ALPHA * mraw;  // bound on leakyrelu(e)
    const float mm = mle * LOG2E;
    const float sm = s[i0 + l16];

    f32x4 acc0 = {0,0,0,0}, acc1 = {0,0,0,0}, acc2 = {0,0,0,0}, acc3 = {0,0,0,0};
    float lsum = 0.f;

#pragma unroll 4
    for (int u = 0; u < UNITS; ++u) {
        proc_unit(A0[u & 3], A1[u & 3], T0[u & 1], T1[u & 1],
                  B0[u & 1], B1[u & 1], B2[u & 1], B3[u & 1],
                  sm, mm, acc0, acc1, acc2, acc3, lsum);
        // refill adj slot for u+4 (clamped: tail re-reads last unit, L2-hot, branch-free)
        int ua = u + 4; if (ua > UNITS - 1) ua = UNITS - 1;
        A0[u & 3] = *(const float4*)(arow + ua * 32);
        A1[u & 3] = *(const float4*)(arow + ua * 32 + 4);
        // refill t/B slot for u+2
        int ub = u + 2; if (ub > UNITS - 1) ub = UNITS - 1;
        T0[u & 1] = *(const float4*)(trow + ub * 32);
        T1[u & 1] = *(const float4*)(trow + ub * 32 + 4);
        const size_t cidx = ((size_t)(wave * UNITS + ub)) * 4;
        B0[u & 1] = BF[(cidx + 0) * 64 + lane];
        B1[u & 1] = BF[(cidx + 1) * 64 + lane];
        B2[u & 1] = BF[(cidx + 2) * 64 + lane];
        B3[u & 1] = BF[(cidx + 3) * 64 + lane];
    }

    // row-sum of p across the wave: lanes {m, m+16, m+32, m+48} hold row m partials
    lsum += __shfl_xor(lsum, 16);
    lsum += __shfl_xor(lsum, 32);

    // stash per-wave partials
#pragma unroll
    for (int r = 0; r < 4; ++r) {
        shacc[wave][0][lane][r] = acc0[r];
        shacc[wave][1][lane][r] = acc1[r];
        shacc[wave][2][lane][r] = acc2[r];
        shacc[wave][3][lane][r] = acc3[r];
    }
    if (lane < 16) shl[wave][lane] = lsum;
    __syncthreads();

    if (wave == 4 && lane < 16) {  // combine row sums
        float v = 0.f;
#pragma unroll
        for (int w = 0; w < 8; ++w) v += shl[w][lane];
        shl[0][lane] = v;
    }
    float tot[4] = {0.f, 0.f, 0.f, 0.f};
    if (wave < 4) {  // wave w reduces + outputs col-tile w
#pragma unroll
        for (int w = 0; w < 8; ++w) {
            float4 c = *(const float4*)&shacc[w][wave][lane][0];
#pragma unroll
            for (int r = 0; r < 4; ++r) tot[r] += ((const float*)&c)[r];
        }
    }
    __syncthreads();
    if (wave < 4) {
#pragma unroll
        for (int r = 0; r < 4; ++r) {
            int row = quad * 4 + r;                      // C/D: row=(lane>>4)*4+reg
            float l = shl[0][row];
            float v = tot[r] / l;
            float o = v > 0.f ? v : (exp2f(v * LOG2E) - 1.f);
            out[(size_t)(i0 + row) * FOUT + wave * 16 + l16] = o;
        }
    }
}

extern "C" void kernel_launch(void* const* d_in, const int* in_sizes, int n_in,
                              void* d_out, int out_size, void* d_ws, size_t ws_size,
                              hipStream_t stream) {
    const float* h   = (const float*)d_in[0];
    const float* adj = (const float*)d_in[1];
    const float* W   = (const float*)d_in[2];
    const float* a   = (const float*)d_in[3];
    float* out = (float*)d_out;

    // ws: Wh fp32 (2 MB) | WhB bf16 (1 MB) | s (32 KB) | t (32 KB) | keys (8 B)
    float* Wh = (float*)d_ws;
    __hip_bfloat16* WhB = (__hip_bfloat16*)(Wh + (size_t)N * FOUT);
    float* s = (float*)(WhB + (size_t)N * FOUT);
    float* t = s + N;
    unsigned* keys = (unsigned*)(t + N);

    hipMemsetAsync(keys, 0, 2 * sizeof(unsigned), stream);
    k_prep<<<N / 16, 256, 0, stream>>>(h, W, a, Wh, s, t, keys);
    k_pack<<<N / 32, 256, 0, stream>>>(Wh, WhB);
    k_attn<<<N / 16, 512, 0, stream>>>(adj, WhB, s, t, keys, out);
}

// Round 5
// 429.568 us; speedup vs baseline: 1.0315x; 1.0315x over previous
//
#include <hip/hip_runtime.h>
#include <hip/hip_bf16.h>

#define N 8192
#define FIN 128
#define FOUT 64
#define ALPHA 0.2f
#define LOG2E 1.44269504f
#define STJ 256               // j per stage
#define NSTAGES (N / STJ)     // 32
#define RS 260                // LDS row stride (floats), padded: bank-conflict-free

typedef __attribute__((ext_vector_type(8))) short short8;
typedef __attribute__((ext_vector_type(4))) float f32x4;

static __device__ __forceinline__ unsigned fkey(float x) {
    unsigned u = __float_as_uint(x);
    return (u >> 31) ? ~u : (u | 0x80000000u);
}
static __device__ __forceinline__ float fdecode(unsigned k) {
    unsigned u = (k & 0x80000000u) ? (k & 0x7FFFFFFFu) : ~k;
    return __uint_as_float(u);
}

// async global->LDS DMA: per-lane 16B from g (lane's own addr); LDS dest =
// wave-uniform base + lane*16 (m104 semantics). Cannot be sunk by the scheduler.
static __device__ __forceinline__ void gll16(const float* g, float* l) {
    __builtin_amdgcn_global_load_lds(
        (const __attribute__((address_space(1))) unsigned int*)g,
        (__attribute__((address_space(3))) unsigned int*)l, 16, 0, 0);
}

// ---------------- k_prep: Wh = h@W (fp32), s = Wh@a1, t = Wh@a2, global max keys ----
__global__ __launch_bounds__(256) void k_prep(const float* __restrict__ h,
                                              const float* __restrict__ W,
                                              const float* __restrict__ a,
                                              float* __restrict__ Wh,
                                              float* __restrict__ s,
                                              float* __restrict__ t,
                                              unsigned* __restrict__ keys) {
    __shared__ float lH[16 * FIN];    // 8 KB
    __shared__ float lW[FIN * FOUT];  // 32 KB
    __shared__ float red[8];
    const int tid = threadIdx.x;
    const int r0 = blockIdx.x * 16;
    {   // coalesced float4 staging
        const float4* src = (const float4*)(h + (size_t)r0 * FIN);
        float4* dst = (float4*)lH;
        for (int i = tid; i < 16 * FIN / 4; i += 256) dst[i] = src[i];
        const float4* ws_ = (const float4*)W;
        float4* dw = (float4*)lW;
        for (int i = tid; i < FIN * FOUT / 4; i += 256) dw[i] = ws_[i];
    }
    __syncthreads();
    const int wave = tid >> 6, lane = tid & 63;
    float acc[4] = {0.f, 0.f, 0.f, 0.f};
    for (int k = 0; k < FIN; ++k) {
        float wv = lW[k * FOUT + lane];
#pragma unroll
        for (int r = 0; r < 4; ++r)
            acc[r] = fmaf(lH[(wave * 4 + r) * FIN + k], wv, acc[r]);
    }
    const float a1 = a[lane], a2 = a[FOUT + lane];
    float smx = -1e30f, tmx = -1e30f;
#pragma unroll
    for (int r = 0; r < 4; ++r) {
        int row = r0 + wave * 4 + r;
        Wh[(size_t)row * FOUT + lane] = acc[r];
        float sv = acc[r] * a1, tv = acc[r] * a2;
#pragma unroll
        for (int off = 32; off; off >>= 1) {
            sv += __shfl_xor(sv, off);
            tv += __shfl_xor(tv, off);
        }
        if (lane == 0) { s[row] = sv; t[row] = tv; }
        smx = fmaxf(smx, sv);
        tmx = fmaxf(tmx, tv);
    }
    if (lane == 0) { red[wave] = smx; red[4 + wave] = tmx; }
    __syncthreads();
    if (tid == 0) {
        float ms = fmaxf(fmaxf(red[0], red[1]), fmaxf(red[2], red[3]));
        float mt = fmaxf(fmaxf(red[4], red[5]), fmaxf(red[6], red[7]));
        atomicMax(keys + 0, fkey(ms));
        atomicMax(keys + 1, fkey(mt));
    }
}

// ---------------- k_pack: Wh fp32 -> bf16 B-fragment layout ------------------------
// B-frag (16x16x32): lane holds col n = lane&15, k = (lane>>4)*8 + e, e=0..7
__global__ __launch_bounds__(256) void k_pack(const float* __restrict__ Wh,
                                              __hip_bfloat16* __restrict__ WhB) {
    const int c = blockIdx.x;            // k-chunk 0..255
    const int tn = threadIdx.x >> 6;     // col tile 0..3
    const int lane = threadIdx.x & 63;
    const int quad = lane >> 4, l16 = lane & 15;
    const float* src = Wh + ((size_t)(c * 32 + quad * 8)) * FOUT + tn * 16 + l16;
    union { unsigned short u[8]; short8 v; } frag;
#pragma unroll
    for (int e = 0; e < 8; ++e) {
        __hip_bfloat16 b = __float2bfloat16(src[(size_t)e * FOUT]);
        frag.u[e] = *(unsigned short*)&b;
    }
    *(short8*)&WhB[(((size_t)c * 4 + tn) * 64 + lane) * 8] = frag.v;
}

// ---------------- k_attn: fused mask+softmax+PV, m97-style LDS pipeline ------------
// Block: 512 thr = 8 waves; block owns 16 rows. Stage = 16 rows x 256 j of adj
// (16.6 KB padded) DMA'd to LDS double-buffered. Wave w: col-tile ct=w&3,
// j-half jh=w>>2 (128 j = 4 K-chunks of 32). All waves compute identical p for
// their j-half (redundant exp, cheap); lsum published by ct==0 waves only.
__global__ __launch_bounds__(512) void k_attn(const float* __restrict__ adj,
                                              const __hip_bfloat16* __restrict__ WhB,
                                              const float* __restrict__ s,
                                              const float* __restrict__ t,
                                              const unsigned* __restrict__ keys,
                                              float* __restrict__ out) {
    __shared__ float bufA[2][16 * RS];   // 2 x 16640 B adj stages
    __shared__ float bufT[2][STJ];       // 2 x 1 KB t stages
    __shared__ float shacc[8][64][4];    // 8 KB epilogue
    __shared__ float shl[2][16];
    const int wave = threadIdx.x >> 6, lane = threadIdx.x & 63;
    const int quad = lane >> 4, l16 = lane & 15;
    const int ct = wave & 3, jh = wave >> 2;
    const int i0 = blockIdx.x * 16;

    const float mraw = fdecode(keys[0]) + fdecode(keys[1]);
    const float mle = mraw > 0.f ? mraw : ALPHA * mraw;
    const float mm = mle * LOG2E;
    const float sm = s[i0 + l16];
    const short8* BF = (const short8*)WhB;

    f32x4 acc = {0, 0, 0, 0};
    float lsum = 0.f;

    // stage(st, b): wave stages its 2 adj rows; wave 0 also t. 17 KB in flight/block.
    const int r2 = 2 * wave;
    const float* gadj = adj + (size_t)(i0 + r2) * N + lane * 4;

    // prologue: stage 0
    gll16(gadj, &bufA[0][r2 * RS]);
    gll16(gadj + N, &bufA[0][(r2 + 1) * RS]);
    if (wave == 0) gll16(t + lane * 4, &bufT[0][0]);
    __syncthreads();

    for (int st = 0; st < NSTAGES; ++st) {
        const int b = st & 1;
        if (st + 1 < NSTAGES) {  // DMA next stage into the other buffer
            const float* g = gadj + (size_t)(st + 1) * STJ;
            gll16(g, &bufA[b ^ 1][r2 * RS]);
            gll16(g + N, &bufA[b ^ 1][(r2 + 1) * RS]);
            if (wave == 0) gll16(t + (size_t)(st + 1) * STJ + lane * 4, &bufT[b ^ 1][0]);
        }
        const float* A = &bufA[b][0];
        const float* T = &bufT[b][0];
        const int cbase = st * 8 + jh * 4;  // global K-chunk base for this wave
        short8 Bf0 = BF[((cbase + 0) * 4 + ct) * 64 + lane];
        short8 Bf1 = BF[((cbase + 1) * 4 + ct) * 64 + lane];
        short8 Bf2 = BF[((cbase + 2) * 4 + ct) * 64 + lane];
        short8 Bf3 = BF[((cbase + 3) * 4 + ct) * 64 + lane];
#pragma unroll
        for (int u = 0; u < 4; ++u) {
            const int j0 = jh * 128 + u * 32 + quad * 8;  // within stage
            float4 a0 = *(const float4*)&A[l16 * RS + j0];
            float4 a1 = *(const float4*)&A[l16 * RS + j0 + 4];
            float4 t0 = *(const float4*)&T[j0];
            float4 t1 = *(const float4*)&T[j0 + 4];
            union { unsigned short u16[8]; short8 v; } af;
#pragma unroll
            for (int e = 0; e < 8; ++e) {
                float av = (e < 4) ? ((const float*)&a0)[e] : ((const float*)&a1)[e - 4];
                float tv = (e < 4) ? ((const float*)&t0)[e] : ((const float*)&t1)[e - 4];
                float x = sm + tv;
                float le = fmaxf(x, ALPHA * x);
                float ex = exp2f(fmaf(le, LOG2E, -mm));
                float p = av * ex;
                __hip_bfloat16 pb = __float2bfloat16(p);
                unsigned short ub = *(unsigned short*)&pb;
                af.u16[e] = ub;
                lsum += __uint_as_float(((unsigned)ub) << 16);  // consistent num/denom
            }
            const short8 bb = (u == 0) ? Bf0 : (u == 1) ? Bf1 : (u == 2) ? Bf2 : Bf3;
            acc = __builtin_amdgcn_mfma_f32_16x16x32_bf16(af.v, bb, acc, 0, 0, 0);
        }
        __syncthreads();  // next-stage DMA drained + all waves done reading buf b
    }

    // lsum: lanes {m, m+16, m+32, m+48} hold row-m partials (over this wave's j-half)
    lsum += __shfl_xor(lsum, 16);
    lsum += __shfl_xor(lsum, 32);
#pragma unroll
    for (int r = 0; r < 4; ++r) shacc[wave][lane][r] = acc[r];
    if (ct == 0 && lane < 16) shl[jh][lane] = lsum;
    __syncthreads();

    if (wave < 4) {  // wave w outputs col-tile w: combine j-halves (w, w+4)
#pragma unroll
        for (int r = 0; r < 4; ++r) {
            float tot = shacc[wave][lane][r] + shacc[wave + 4][lane][r];
            int row = quad * 4 + r;  // C/D: row=(lane>>4)*4+reg
            float l = shl[0][row] + shl[1][row];
            float v = tot / l;
            float o = v > 0.f ? v : (exp2f(v * LOG2E) - 1.f);
            out[(size_t)(i0 + row) * FOUT + wave * 16 + l16] = o;
        }
    }
}

extern "C" void kernel_launch(void* const* d_in, const int* in_sizes, int n_in,
                              void* d_out, int out_size, void* d_ws, size_t ws_size,
                              hipStream_t stream) {
    const float* h   = (const float*)d_in[0];
    const float* adj = (const float*)d_in[1];
    const float* W   = (const float*)d_in[2];
    const float* a   = (const float*)d_in[3];
    float* out = (float*)d_out;

    // ws: Wh fp32 (2 MB) | WhB bf16 (1 MB) | s (32 KB) | t (32 KB) | keys (8 B)
    float* Wh = (float*)d_ws;
    __hip_bfloat16* WhB = (__hip_bfloat16*)(Wh + (size_t)N * FOUT);
    float* s = (float*)(WhB + (size_t)N * FOUT);
    float* t = s + N;
    unsigned* keys = (unsigned*)(t + N);

    hipMemsetAsync(keys, 0, 2 * sizeof(unsigned), stream);
    k_prep<<<N / 16, 256, 0, stream>>>(h, W, a, Wh, s, t, keys);
    k_pack<<<N / 32, 256, 0, stream>>>(Wh, WhB);
    k_attn<<<N / 16, 512, 0, stream>>>(adj, WhB, s, t, keys, out);
}

// Round 6
// 415.713 us; speedup vs baseline: 1.0659x; 1.0333x over previous
//
#include <hip/hip_runtime.h>
#include <hip/hip_bf16.h>

#define N 8192
#define FIN 128
#define FOUT 64
#define ALPHA 0.2f
#define LOG2E 1.44269504f
#define JSPLIT 4
#define JSPAN (N / JSPLIT)      // 2048 j per block
#define STJ 128                 // j per stage (4 units of 32)
#define NST (JSPAN / STJ)       // 16 stages

typedef __attribute__((ext_vector_type(8))) short short8;
typedef __attribute__((ext_vector_type(4))) float f32x4;

static __device__ __forceinline__ unsigned fkey(float x) {
    unsigned u = __float_as_uint(x);
    return (u >> 31) ? ~u : (u | 0x80000000u);
}
static __device__ __forceinline__ float fdecode(unsigned k) {
    unsigned u = (k & 0x80000000u) ? (k & 0x7FFFFFFFu) : ~k;
    return __uint_as_float(u);
}
// async global->LDS DMA: per-lane 16B gather; LDS dest = wave-uniform base + lane*16.
static __device__ __forceinline__ void gll16(const float* g, float* l) {
    __builtin_amdgcn_global_load_lds(
        (const __attribute__((address_space(1))) unsigned int*)g,
        (__attribute__((address_space(3))) unsigned int*)l, 16, 0, 0);
}

// ---------------- k_prep: Wh = h@W; s2 = (Wh@a1)*log2e; t2 = (Wh@a2)*log2e --------
__global__ __launch_bounds__(256) void k_prep(const float* __restrict__ h,
                                              const float* __restrict__ W,
                                              const float* __restrict__ a,
                                              float* __restrict__ Wh,
                                              float* __restrict__ s2,
                                              float* __restrict__ t2,
                                              unsigned* __restrict__ keys) {
    __shared__ float lH[16 * FIN];
    __shared__ float lW[FIN * FOUT];
    __shared__ float red[8];
    const int tid = threadIdx.x;
    const int r0 = blockIdx.x * 16;
    {
        const float4* src = (const float4*)(h + (size_t)r0 * FIN);
        float4* dst = (float4*)lH;
        for (int i = tid; i < 16 * FIN / 4; i += 256) dst[i] = src[i];
        const float4* ws_ = (const float4*)W;
        float4* dw = (float4*)lW;
        for (int i = tid; i < FIN * FOUT / 4; i += 256) dw[i] = ws_[i];
    }
    __syncthreads();
    const int wave = tid >> 6, lane = tid & 63;
    float acc[4] = {0.f, 0.f, 0.f, 0.f};
    for (int k = 0; k < FIN; ++k) {
        float wv = lW[k * FOUT + lane];
#pragma unroll
        for (int r = 0; r < 4; ++r)
            acc[r] = fmaf(lH[(wave * 4 + r) * FIN + k], wv, acc[r]);
    }
    const float a1 = a[lane], a2 = a[FOUT + lane];
    float smx = -1e30f, tmx = -1e30f;
#pragma unroll
    for (int r = 0; r < 4; ++r) {
        int row = r0 + wave * 4 + r;
        Wh[(size_t)row * FOUT + lane] = acc[r];
        float sv = acc[r] * a1, tv = acc[r] * a2;
#pragma unroll
        for (int off = 32; off; off >>= 1) {
            sv += __shfl_xor(sv, off);
            tv += __shfl_xor(tv, off);
        }
        sv *= LOG2E; tv *= LOG2E;      // pre-scale: exp(x) -> exp2(x')
        if (lane == 0) { s2[row] = sv; t2[row] = tv; }
        smx = fmaxf(smx, sv);
        tmx = fmaxf(tmx, tv);
    }
    if (lane == 0) { red[wave] = smx; red[4 + wave] = tmx; }
    __syncthreads();
    if (tid == 0) {
        float ms = fmaxf(fmaxf(red[0], red[1]), fmaxf(red[2], red[3]));
        float mt = fmaxf(fmaxf(red[4], red[5]), fmaxf(red[6], red[7]));
        atomicMax(keys + 0, fkey(ms));
        atomicMax(keys + 1, fkey(mt));
    }
}

// ---------------- k_pack: Wh fp32 -> bf16 B-fragment layout ------------------------
__global__ __launch_bounds__(256) void k_pack(const float* __restrict__ Wh,
                                              __hip_bfloat16* __restrict__ WhB) {
    const int c = blockIdx.x;
    const int tn = threadIdx.x >> 6;
    const int lane = threadIdx.x & 63;
    const int quad = lane >> 4, l16 = lane & 15;
    const float* src = Wh + ((size_t)(c * 32 + quad * 8)) * FOUT + tn * 16 + l16;
    union { unsigned short u[8]; short8 v; } frag;
#pragma unroll
    for (int e = 0; e < 8; ++e) {
        __hip_bfloat16 b = __float2bfloat16(src[(size_t)e * FOUT]);
        frag.u[e] = *(unsigned short*)&b;
    }
    *(short8*)&WhB[(((size_t)c * 4 + tn) * 64 + lane) * 8] = frag.v;
}

// ---------------- k_attn: fused mask+softmax+PV --------------------------------
// Grid (N/16, JSPLIT); block 256 thr = 4 waves owns 16 rows x 2048 j.
// Stage = 128 j = 4 units of 32; wave w owns unit w (zero redundancy) and all
// 4 col-tiles. adj DMA'd in A-frag order: lane (q,l16) gets adj[l16][8q+e] at
// LDS base+lane*16 -> conflict-free ds_read_b128. Partials atomicAdd'd to ws.
__global__ __launch_bounds__(256) void k_attn(const float* __restrict__ adj,
                                              const __hip_bfloat16* __restrict__ WhB,
                                              const float* __restrict__ s2,
                                              const float* __restrict__ t2,
                                              const unsigned* __restrict__ keys,
                                              float* __restrict__ acc_ws,
                                              float* __restrict__ l_ws) {
    __shared__ float smem[2 * 4 * 512];  // 16 KB: [buf][unit][512]; reused in epilogue
    __shared__ float smT[2][256];        // 2 KB t stages (first 512 B valid)
    __shared__ float shl[4][16];
    const int wave = threadIdx.x >> 6, lane = threadIdx.x & 63;
    const int quad = lane >> 4, l16 = lane & 15;
    const int i0 = blockIdx.x * 16;
    const int jbase = blockIdx.y * JSPAN;

    const float mraw = fdecode(keys[0]) + fdecode(keys[1]);  // scaled maxima
    const float mm = mraw > 0.f ? mraw : ALPHA * mraw;       // = leakyrelu(max)*log2e
    const float sm = s2[i0 + l16];
    const short8* BF = (const short8*)WhB;

    // per-lane gather base for this wave's unit: row l16, j = jbase + wave*32 + 8q
    const float* ga = adj + (size_t)(i0 + l16) * N + jbase + wave * 32 + quad * 8;
    const float* gt = t2 + jbase + lane * 4;

    f32x4 acc0 = {0,0,0,0}, acc1 = {0,0,0,0}, acc2 = {0,0,0,0}, acc3 = {0,0,0,0};
    float lsum = 0.f;

    // prologue: stage 0
    gll16(ga, smem + wave * 512);
    gll16(ga + 4, smem + wave * 512 + 256);
    if (wave == 0) gll16(gt, smT[0]);
    __syncthreads();

    for (int st = 0; st < NST; ++st) {
        const int b = st & 1;
        if (st + 1 < NST) {  // DMA next stage
            const float* g = ga + (size_t)(st + 1) * STJ;
            float* lb = smem + (b ^ 1) * 2048 + wave * 512;
            gll16(g, lb);
            gll16(g + 4, lb + 256);
            if (wave == 0) gll16(gt + (size_t)(st + 1) * STJ, smT[b ^ 1]);
        }
        // B fragments for this wave's K-chunk (L2-resident)
        const int kc = blockIdx.y * (JSPAN / 32) + st * 4 + wave;
        short8 Bf0 = BF[((size_t)kc * 4 + 0) * 64 + lane];
        short8 Bf1 = BF[((size_t)kc * 4 + 1) * 64 + lane];
        short8 Bf2 = BF[((size_t)kc * 4 + 2) * 64 + lane];
        short8 Bf3 = BF[((size_t)kc * 4 + 3) * 64 + lane];
        // conflict-free LDS reads (consecutive lanes -> consecutive banks)
        const float* Au = smem + b * 2048 + wave * 512;
        float4 alo = *(const float4*)(Au + (lane << 2));
        float4 ahi = *(const float4*)(Au + 256 + (lane << 2));
        const float* Tu = smT[b] + wave * 32 + quad * 8;
        float4 tlo = *(const float4*)(Tu);
        float4 thi = *(const float4*)(Tu + 4);

        union { __hip_bfloat162 h2[4]; short8 v; } af;
#pragma unroll
        for (int pp = 0; pp < 4; ++pp) {
            float a0 = (pp < 2) ? ((const float*)&alo)[2 * pp]     : ((const float*)&ahi)[2 * pp - 4];
            float a1 = (pp < 2) ? ((const float*)&alo)[2 * pp + 1] : ((const float*)&ahi)[2 * pp - 3];
            float t0 = (pp < 2) ? ((const float*)&tlo)[2 * pp]     : ((const float*)&thi)[2 * pp - 4];
            float t1 = (pp < 2) ? ((const float*)&tlo)[2 * pp + 1] : ((const float*)&thi)[2 * pp - 3];
            float x0 = sm + t0,            x1 = sm + t1;
            float le0 = fmaxf(x0, ALPHA * x0), le1 = fmaxf(x1, ALPHA * x1);
            float p0 = a0 * exp2f(le0 - mm),   p1 = a1 * exp2f(le1 - mm);
            __hip_bfloat162 pb = __float22bfloat162_rn(make_float2(p0, p1));
            af.h2[pp] = pb;
            lsum += __bfloat162float(pb.x) + __bfloat162float(pb.y);  // consistent
        }
        acc0 = __builtin_amdgcn_mfma_f32_16x16x32_bf16(af.v, Bf0, acc0, 0, 0, 0);
        acc1 = __builtin_amdgcn_mfma_f32_16x16x32_bf16(af.v, Bf1, acc1, 0, 0, 0);
        acc2 = __builtin_amdgcn_mfma_f32_16x16x32_bf16(af.v, Bf2, acc2, 0, 0, 0);
        acc3 = __builtin_amdgcn_mfma_f32_16x16x32_bf16(af.v, Bf3, acc3, 0, 0, 0);
        __syncthreads();  // drains next-stage DMA; frees buf b
    }

    // lsum: lanes {m, m+16, m+32, m+48} hold row-m partials for this wave's chunks
    lsum += __shfl_xor(lsum, 16);
    lsum += __shfl_xor(lsum, 32);

    // epilogue: reuse smem (16 KB) as accr[4 waves][4 tiles][64 lanes][4]
    float* accr = smem;
    *(f32x4*)&accr[((wave * 4 + 0) * 64 + lane) * 4] = acc0;
    *(f32x4*)&accr[((wave * 4 + 1) * 64 + lane) * 4] = acc1;
    *(f32x4*)&accr[((wave * 4 + 2) * 64 + lane) * 4] = acc2;
    *(f32x4*)&accr[((wave * 4 + 3) * 64 + lane) * 4] = acc3;
    if (lane < 16) shl[wave][lane] = lsum;
    __syncthreads();

    const int tile = wave;
    f32x4 tot = {0, 0, 0, 0};
#pragma unroll
    for (int w = 0; w < 4; ++w) {
        f32x4 c = *(const f32x4*)&accr[((w * 4 + tile) * 64 + lane) * 4];
        tot[0] += c[0]; tot[1] += c[1]; tot[2] += c[2]; tot[3] += c[3];
    }
#pragma unroll
    for (int r = 0; r < 4; ++r) {
        int row = quad * 4 + r;  // C/D: row=(lane>>4)*4+reg
        atomicAdd(&acc_ws[(size_t)(i0 + row) * FOUT + tile * 16 + l16], tot[r]);
    }
    if (wave == 0 && lane < 16) {
        float lv = shl[0][lane] + shl[1][lane] + shl[2][lane] + shl[3][lane];
        atomicAdd(&l_ws[i0 + lane], lv);
    }
}

// ---------------- k_final: out = elu(acc/l) ---------------------------------------
__global__ __launch_bounds__(256) void k_final(const float* __restrict__ acc_ws,
                                               const float* __restrict__ l_ws,
                                               float* __restrict__ out) {
    const int idx = blockIdx.x * 256 + threadIdx.x;   // one float4 per thread
    const int row = idx >> 4;                          // 16 float4 per row
    const float inv = 1.0f / l_ws[row];
    float4 a = ((const float4*)acc_ws)[idx];
    float4 o;
#pragma unroll
    for (int r = 0; r < 4; ++r) {
        float v = ((const float*)&a)[r] * inv;
        ((float*)&o)[r] = v > 0.f ? v : (exp2f(v * LOG2E) - 1.f);
    }
    ((float4*)out)[idx] = o;
}

extern "C" void kernel_launch(void* const* d_in, const int* in_sizes, int n_in,
                              void* d_out, int out_size, void* d_ws, size_t ws_size,
                              hipStream_t stream) {
    const float* h   = (const float*)d_in[0];
    const float* adj = (const float*)d_in[1];
    const float* W   = (const float*)d_in[2];
    const float* a   = (const float*)d_in[3];
    float* out = (float*)d_out;

    float* Wh = (float*)d_ws;                                   // N*64 f
    __hip_bfloat16* WhB = (__hip_bfloat16*)(Wh + (size_t)N * FOUT);  // N*64 bf16
    float* s2 = (float*)(WhB + (size_t)N * FOUT);               // N f
    float* t2 = s2 + N;                                          // N f
    float* pad = t2 + N;                                         // 256 f slack (t DMA overrun)
    float* acc_ws = pad + 256;                                   // N*64 f (zeroed)
    float* l_ws = acc_ws + (size_t)N * FOUT;                     // N f (zeroed)
    unsigned* keys = (unsigned*)(l_ws + N);                      // 2 u32 (zeroed)

    hipMemsetAsync(acc_ws, 0, ((size_t)N * FOUT + N) * sizeof(float) + 2 * sizeof(unsigned),
                   stream);
    k_prep<<<N / 16, 256, 0, stream>>>(h, W, a, Wh, s2, t2, keys);
    k_pack<<<N / 32, 256, 0, stream>>>(Wh, WhB);
    dim3 ag(N / 16, JSPLIT);
    k_attn<<<ag, 256, 0, stream>>>(adj, WhB, s2, t2, keys, acc_ws, l_ws);
    k_final<<<(N * FOUT / 4) / 256, 256, 0, stream>>>(acc_ws, l_ws, out);
}